// Round 13
// baseline (138.630 us; speedup 1.0000x reference)
//
#include <hip/hip_runtime.h>
#include <hip/hip_bf16.h>
#include <math.h>

#define T_ 16
#define B_ 1024
#define F_ 512
#define H_ 128
#define D_ 8
#define C_ 100
#define L_ 512
#define CP_ 112   // C padded to multiple of 16 for MFMA N

typedef __attribute__((ext_vector_type(8))) short bf16x8_t;
typedef __attribute__((ext_vector_type(4))) float f32x4_t;

__device__ inline ushort f2bf(float x) {
  __hip_bfloat16 b = __float2bfloat16(x);
  return *(ushort*)&b;
}
__device__ inline float bf2f(ushort u) {
  union { unsigned int i; float f; } v;
  v.i = ((unsigned int)u) << 16;
  return v.f;
}

// Raw barrier helpers: NO vmcnt drain (prefetch loads stay in flight).
__device__ inline void bar_raw() {
  asm volatile("" ::: "memory");
  __builtin_amdgcn_s_barrier();
  asm volatile("" ::: "memory");
}
__device__ inline void bar_publish_lds() {
  asm volatile("s_waitcnt lgkmcnt(0)" ::: "memory");
  __builtin_amdgcn_s_barrier();
  asm volatile("" ::: "memory");
}

// ---------------------------------------------------------------------------
// k_prep: vectorized transposes (64x64 f32 tiles, float4 loads = 16B/lane,
// bf16x8 stores) + softmax.  Grid 768 (was 2304).
//   [0,256)    : W1 [t][F][H] -> W1T [t][H][F] bf16   (16 tiles x 16 t)
//   [256,512)  : W2 [t][H][L] -> W2T [t][L][H] bf16   (16 tiles x 16 t)
//   [512,768)  : softmax(pi) -> lpT[t][c][l], coalesced 16B stores.
// ---------------------------------------------------------------------------
__global__ __launch_bounds__(256) void k_prep(
    const float* __restrict__ W1, const float* __restrict__ W2,
    const float* __restrict__ pi, ushort* __restrict__ W1T,
    ushort* __restrict__ W2T, ushort* __restrict__ lpT) {
  __shared__ float tile[64][68];                     // 17408 B (68: 16B-aligned rows)
  ushort (*tileT)[48] = (ushort(*)[48])tile;         // softmax path alias
  const int bid = blockIdx.x, tid = threadIdx.x;

  if (bid < 512) {  // ---- transposes, 64x64 tiles
    const float* X; ushort* XT; int K, N, kb, nb, s;
    if (bid < 256) {
      int u = bid & 15;  kb = u & 7;  nb = (u >> 3) & 1;  s = bid >> 4;
      X = W1; XT = W1T; K = F_; N = H_;
    } else {
      int r = bid - 256; int u = r & 15; kb = u & 1; nb = (u >> 1) & 7; s = r >> 4;
      X = W2; XT = W2T; K = H_; N = L_;
    }
    const int k0 = kb * 64, n0 = nb * 64;
    const float* Xs = X + (size_t)s * K * N;
    ushort* XTs = XT + (size_t)s * N * K;
    {
      const int rrow = tid >> 4, c4 = (tid & 15) * 4;
#pragma unroll
      for (int j = 0; j < 4; ++j) {
        float4 v = *(const float4*)(Xs + (size_t)(k0 + j * 16 + rrow) * N + n0 + c4);
        *(float4*)&tile[j * 16 + rrow][c4] = v;
      }
    }
    __syncthreads();
    {
      const int k8 = (tid & 7) * 8;
#pragma unroll
      for (int pass = 0; pass < 2; ++pass) {
        int rr = pass * 32 + (tid >> 3);
        bf16x8_t o;
#pragma unroll
        for (int i = 0; i < 8; ++i) o[i] = (short)f2bf(tile[k8 + i][rr]);
        *(bf16x8_t*)(XTs + (size_t)(n0 + rr) * K + k0 + k8) = o;
      }
    }
    return;
  }
  {  // ---- softmax of 32 rows -> LDS transpose -> coalesced lpT[t][c][l]
    int bid2 = bid - 512;                  // [0,256)
    int t = bid2 >> 4, l0 = (bid2 & 15) << 5;
    int lane = tid & 63;
#pragma unroll
    for (int p = 0; p < 8; ++p) {
      int rl = p * 4 + (tid >> 6);
      const float* x = pi + (size_t)(t * L_ + l0 + rl) * C_;
      float v0 = (lane < C_) ? x[lane] : -1e30f;
      float v1 = (lane + 64 < C_) ? x[lane + 64] : -1e30f;
      float m = fmaxf(v0, v1);
#pragma unroll
      for (int off = 32; off; off >>= 1) m = fmaxf(m, __shfl_xor(m, off, 64));
      float e0 = __expf(v0 - m);
      float e1 = (lane + 64 < C_) ? __expf(v1 - m) : 0.0f;
      float sm = e0 + e1;
#pragma unroll
      for (int off = 32; off; off >>= 1) sm += __shfl_xor(sm, off, 64);
      float inv = 1.0f / sm;
      if (lane < C_) tileT[lane][rl] = f2bf(e0 * inv);
      int c2 = lane + 64;
      if (c2 < CP_) tileT[c2][rl] = f2bf(c2 < C_ ? e1 * inv : 0.0f);
    }
    __syncthreads();
    ushort* dst = lpT + (size_t)t * CP_ * L_ + l0;
    for (int idx = tid; idx < 448; idx += 256) {       // 112 c x 4 chunks
      int c = idx >> 2, ch = (idx & 3) * 8;
      *(bf16x8_t*)(dst + (size_t)c * L_ + ch) = *(const bf16x8_t*)&tileT[c][ch];
    }
  }
}

// ---------------------------------------------------------------------------
// k12: r11 structure VERBATIM (dbuf staging, counted-vmcnt barriers, fused
// feat cvt) + k6 folded into the tail: GEMM3 writes part with PLAIN stores
// (r12's atomicAdd storm removed), then the last-arriving block per 32-row
// chunk (r12-validated fence+counter pattern) sums part over t ASCENDING
// (= k6's exact order, bit-identical) and writes log -> out.
// ---------------------------------------------------------------------------
__global__ __launch_bounds__(512, 4) void k12_mfma(
    const float* __restrict__ feat, const ushort* __restrict__ W1T,
    const float* __restrict__ b1, const ushort* __restrict__ W2T,
    const float* __restrict__ b2, const ushort* __restrict__ lpT,
    float* __restrict__ part, unsigned int* __restrict__ cnt,
    float* __restrict__ out) {
  __shared__ ushort smem[38400];                        // 76800 B
  ushort (*h_s)[136] = (ushort(*)[136])smem;
  ushort (*a_s0)[72] = (ushort(*)[72])(smem + 4352);
  ushort (*a_s1)[72] = (ushort(*)[72])(smem + 4352 + 2304);
  ushort (*b_s0)[72] = (ushort(*)[72])(smem + 8960);
  ushort (*b_s1)[72] = (ushort(*)[72])(smem + 8960 + 9216);
  ushort (*w_s0)[136] = (ushort(*)[136])(smem + 4352);
  ushort (*w_s1)[136] = (ushort(*)[136])(smem + 4352 + 8704);
  ushort (*p_s)[520] = (ushort(*)[520])(smem + 21760);
  __shared__ unsigned int last_flag;

  const int bid = blockIdx.x;
  const int t = bid & 15, b0 = (bid >> 4) * 32;
  const int tid = threadIdx.x;                          // [0,512)
  const int w = tid >> 6, lane = tid & 63, quad = lane >> 4, n = lane & 15;

  // ---------------- phase 1: h tile (M=32, N=128, K=512) ----------------
  {
    const bool doA = tid < 256;
    const int srow = tid >> 3, scol = (tid & 7) * 8;    // srow: A [0,32), B [0,64)
    const float*  fp32p = feat + (size_t)(b0 + srow) * F_ + scol;   // tid<256
    const ushort* w1p   = W1T + ((size_t)t * H_ + srow) * F_ + scol;

    float4 ra[2][2];           // fp32 A prefetch (2 sets x 8 floats)
    bf16x8_t rb[2][2];         // B prefetch (2 sets x 2 rows)

    // chunk 0 -> set 0, stage immediately (exposed once)
    if (doA) { ra[0][0] = *(const float4*)(fp32p);
               ra[0][1] = *(const float4*)(fp32p + 4); }
#pragma unroll
    for (int i = 0; i < 2; ++i)
      rb[0][i] = *(const bf16x8_t*)(w1p + (size_t)i * 64 * F_);
    if (doA) {
      bf16x8_t o;
      o[0] = (short)f2bf(ra[0][0].x); o[1] = (short)f2bf(ra[0][0].y);
      o[2] = (short)f2bf(ra[0][0].z); o[3] = (short)f2bf(ra[0][0].w);
      o[4] = (short)f2bf(ra[0][1].x); o[5] = (short)f2bf(ra[0][1].y);
      o[6] = (short)f2bf(ra[0][1].z); o[7] = (short)f2bf(ra[0][1].w);
      *(bf16x8_t*)&a_s0[srow][scol] = o;
    }
#pragma unroll
    for (int i = 0; i < 2; ++i)
      *(bf16x8_t*)&b_s0[i * 64 + srow][scol] = rb[0][i];
    bar_publish_lds();                         // B1: chunk 0 visible
    // prefetch chunk 1 -> set 1, chunk 2 -> set 0
    if (doA) { ra[1][0] = *(const float4*)(fp32p + 64);
               ra[1][1] = *(const float4*)(fp32p + 68); }
#pragma unroll
    for (int i = 0; i < 2; ++i)
      rb[1][i] = *(const bf16x8_t*)(w1p + (size_t)i * 64 * F_ + 64);
    if (doA) { ra[0][0] = *(const float4*)(fp32p + 128);
               ra[0][1] = *(const float4*)(fp32p + 132); }
#pragma unroll
    for (int i = 0; i < 2; ++i)
      rb[0][i] = *(const bf16x8_t*)(w1p + (size_t)i * 64 * F_ + 128);

    f32x4_t acc[2];
    acc[0] = (f32x4_t){0.f, 0.f, 0.f, 0.f};
    acc[1] = (f32x4_t){0.f, 0.f, 0.f, 0.f};
#pragma unroll
    for (int kc = 0; kc < 8; ++kc) {
      ushort (*ar)[72] = (kc & 1) ? a_s1 : a_s0;
      ushort (*br)[72] = (kc & 1) ? b_s1 : b_s0;
#pragma unroll
      for (int ks2 = 0; ks2 < 2; ++ks2) {
        const int ko = ks2 * 32 + quad * 8;
        bf16x8_t af0 = *(const bf16x8_t*)&ar[n][ko];
        bf16x8_t af1 = *(const bf16x8_t*)&ar[16 + n][ko];
        bf16x8_t bfr = *(const bf16x8_t*)&br[w * 16 + n][ko];
        acc[0] = __builtin_amdgcn_mfma_f32_16x16x32_bf16(af0, bfr, acc[0],
                                                         0, 0, 0);
        acc[1] = __builtin_amdgcn_mfma_f32_16x16x32_bf16(af1, bfr, acc[1],
                                                         0, 0, 0);
      }
      if (kc < 7) {                            // stage chunk kc+1 -> other buf
        const int p = (kc + 1) & 1;
        ushort (*aw)[72] = p ? a_s1 : a_s0;
        ushort (*bw)[72] = p ? b_s1 : b_s0;
        if (doA) {
          bf16x8_t o;
          o[0] = (short)f2bf(ra[p][0].x); o[1] = (short)f2bf(ra[p][0].y);
          o[2] = (short)f2bf(ra[p][0].z); o[3] = (short)f2bf(ra[p][0].w);
          o[4] = (short)f2bf(ra[p][1].x); o[5] = (short)f2bf(ra[p][1].y);
          o[6] = (short)f2bf(ra[p][1].z); o[7] = (short)f2bf(ra[p][1].w);
          *(bf16x8_t*)&aw[srow][scol] = o;     // counted vmcnt via reg dep
        }
#pragma unroll
        for (int i = 0; i < 2; ++i)
          *(bf16x8_t*)&bw[i * 64 + srow][scol] = rb[p][i];
        bar_publish_lds();                     // ONE barrier per phase
        if (kc < 6) {                          // refill set p with chunk kc+3
          if (doA) { ra[p][0] = *(const float4*)(fp32p + (kc + 3) * 64);
                     ra[p][1] = *(const float4*)(fp32p + (kc + 3) * 64 + 4); }
#pragma unroll
          for (int i = 0; i < 2; ++i)
            rb[p][i] = *(const bf16x8_t*)(w1p + (size_t)i * 64 * F_ + (kc + 3) * 64);
        }
      }
    }
    float bias = b1[t * H_ + w * 16 + n];
#pragma unroll
    for (int mt = 0; mt < 2; ++mt)
#pragma unroll
      for (int r = 0; r < 4; ++r) {
        float v = acc[mt][r] + bias;
        h_s[mt * 16 + quad * 4 + r][w * 16 + n] = f2bf(v > 0.f ? v : 0.f);
      }
  }

  // ---------------- phase 2: GEMM2 + sigmoid -> p_s (dbuf w_s) ----------
  {
    const int wrow = tid >> 4, wcol = (tid & 15) * 8;  // wrow in [0,32)
    const ushort* w2p = W2T + ((size_t)t * L_ + wrow) * H_ + wcol;
    bf16x8_t rw[2][2];
    // issue nc=0,1 loads NOW: fly under the h_s epilogue + barrier
#pragma unroll
    for (int i = 0; i < 2; ++i)
      rw[0][i] = *(const bf16x8_t*)(w2p + (size_t)(i * 32) * H_);
#pragma unroll
    for (int i = 0; i < 2; ++i)
      rw[1][i] = *(const bf16x8_t*)(w2p + (size_t)(64 + i * 32) * H_);
    bar_publish_lds();                         // B2: h_s visible, ph1 dead

    const int mhalf = w >> 2, lhalf = w & 3;   // 2 m-halves x 4 l-tiles
    bf16x8_t af2[4];                           // A frags hoisted
#pragma unroll
    for (int ks = 0; ks < 4; ++ks)
      af2[ks] = *(const bf16x8_t*)&h_s[mhalf * 16 + n][ks * 32 + quad * 8];
#pragma unroll
    for (int i = 0; i < 2; ++i)
      *(bf16x8_t*)&w_s0[i * 32 + wrow][wcol] = rw[0][i];
    bar_publish_lds();                         // w_s(0) visible
#pragma unroll
    for (int i = 0; i < 2; ++i)                // refill set 0 with nc=2
      rw[0][i] = *(const bf16x8_t*)(w2p + (size_t)(128 + i * 32) * H_);

#pragma unroll
    for (int nc = 0; nc < 8; ++nc) {
      ushort (*wr)[136] = (nc & 1) ? w_s1 : w_s0;
      f32x4_t acc = (f32x4_t){0.f, 0.f, 0.f, 0.f};
#pragma unroll
      for (int ks = 0; ks < 4; ++ks) {
        bf16x8_t bfrag = *(const bf16x8_t*)&wr[lhalf * 16 + n][ks * 32 + quad * 8];
        acc = __builtin_amdgcn_mfma_f32_16x16x32_bf16(af2[ks], bfrag, acc,
                                                      0, 0, 0);
      }
      int l = nc * 64 + lhalf * 16 + n;
      float bias = b2[t * L_ + l];
#pragma unroll
      for (int r = 0; r < 4; ++r) {
        float x = acc[r] + bias;
        p_s[mhalf * 16 + quad * 4 + r][l] = f2bf(1.0f / (1.0f + __expf(-x)));
      }
      if (nc < 7) {                            // stage nc+1 -> other buf
        const int p = (nc + 1) & 1;
        ushort (*ww)[136] = p ? w_s1 : w_s0;
#pragma unroll
        for (int i = 0; i < 2; ++i)
          *(bf16x8_t*)&ww[i * 32 + wrow][wcol] = rw[p][i];
        bar_publish_lds();                     // ONE barrier per phase
        if (nc < 6) {
#pragma unroll
          for (int i = 0; i < 2; ++i)
            rw[p][i] = *(const bf16x8_t*)(w2p + (size_t)((nc + 3) * 64 + i * 32) * H_);
        }
      }
    }
  }
  bar_publish_lds();                           // B3: p_s complete

  // ---------------- routing: 1024 units (b,s) over 512 threads, 2 passes --
  bf16x8_t mo[2][2];
#pragma unroll
  for (int pass = 0; pass < 2; ++pass) {
    int unit = pass * 512 + tid;
    int b = unit >> 5;
    int s = unit & 31;
    float P = 1.f;
#pragma unroll
    for (int d = 0; d < 5; ++d) {
      int nd = (1 << d) - 1 + (s >> (5 - d));
      int sd = (s >> (4 - d)) & 1;
      float pv = bf2f(p_s[b][nd]);
      P *= sd ? (1.f - pv) : pv;
    }
    float p5 = bf2f(p_s[b][31 + s]);
    float q5[2] = {P * p5, P * (1.f - p5)};
    float q6[4], q7[8];
#pragma unroll
    for (int j = 0; j < 2; ++j) {
      float pv = bf2f(p_s[b][63 + 2 * s + j]);
      q6[2 * j] = q5[j] * pv;
      q6[2 * j + 1] = q5[j] * (1.f - pv);
    }
#pragma unroll
    for (int u = 0; u < 4; ++u) {
      float pv = bf2f(p_s[b][127 + 4 * s + u]);
      q7[2 * u] = q6[u] * pv;
      q7[2 * u + 1] = q6[u] * (1.f - pv);
    }
    bf16x8_t o0, o1;
#pragma unroll
    for (int v = 0; v < 8; ++v) {
      float pv = bf2f(p_s[b][255 + 8 * s + v]);
      ushort e0 = f2bf(q7[v] * pv);
      ushort e1 = f2bf(q7[v] * (1.f - pv));
      if (v < 4) { o0[2 * v] = (short)e0; o0[2 * v + 1] = (short)e1; }
      else       { o1[2 * (v - 4)] = (short)e0; o1[2 * (v - 4) + 1] = (short)e1; }
    }
    mo[pass][0] = o0;
    mo[pass][1] = o1;
  }
  bar_raw();         // B4: routing reads done -> safe to overwrite p_s
#pragma unroll
  for (int pass = 0; pass < 2; ++pass) {
    int unit = pass * 512 + tid;
    int b = unit >> 5;
    int s = unit & 31;
    *(bf16x8_t*)&p_s[b][s * 16]     = mo[pass][0];   // p_s now holds mu
    *(bf16x8_t*)&p_s[b][s * 16 + 8] = mo[pass][1];
  }
  bar_publish_lds();                           // B5: mu visible

  // ---------------- GEMM3: part = mu @ leaf_p (M=32,N=112,K=512) ----------
  // 14 (mt,nt) units over 8 waves: wave w does unit w, and unit w+8 if w<6.
  {
#pragma unroll
    for (int uu = 0; uu < 2; ++uu) {
      int u = w + uu * 8;
      if (u < 14) {
        const int mt = u & 1, nt = u >> 1;
        const ushort* arow = &p_s[mt * 16 + n][0];
        const ushort* brow = lpT + (size_t)t * CP_ * L_ +
                             ((size_t)(nt * 16 + n)) * L_ + quad * 8;
        f32x4_t acc = (f32x4_t){0.f, 0.f, 0.f, 0.f};
#pragma unroll 4
        for (int k = 0; k < L_; k += 32) {
          bf16x8_t af = *(const bf16x8_t*)(arow + k + quad * 8);
          bf16x8_t bfr = *(const bf16x8_t*)(brow + k);
          acc = __builtin_amdgcn_mfma_f32_16x16x32_bf16(af, bfr, acc, 0, 0, 0);
        }
        const int m0 = b0 + mt * 16 + quad * 4;
        const int c = nt * 16 + n;
        if (c < C_) {
#pragma unroll
          for (int r = 0; r < 4; ++r)
            part[((size_t)t * B_ + m0 + r) * C_ + c] = acc[r];
        }
      }
    }
  }

  // ---------------- last-block-per-chunk: sum over t (ascending) + log ----
  __syncthreads();             // drains vmcnt: all part stores complete
  if (tid == 0) {
    __threadfence();           // writes visible device-wide (L2 writeback)
    unsigned int old = __hip_atomic_fetch_add(&cnt[bid >> 4], 1u,
                                              __ATOMIC_ACQ_REL,
                                              __HIP_MEMORY_SCOPE_AGENT);
    last_flag = (old == 15u) ? 1u : 0u;
  }
  __syncthreads();
  if (last_flag) {
    const float inv = 1.0f / (L_ * T_);
    for (int idx = tid; idx < 32 * C_; idx += 512) {
      float s = 0.f;
#pragma unroll
      for (int tt = 0; tt < T_; ++tt)
        s += __hip_atomic_load(&part[((size_t)tt * B_ + b0) * C_ + idx],
                               __ATOMIC_RELAXED, __HIP_MEMORY_SCOPE_AGENT);
      out[(size_t)b0 * C_ + idx] = logf(s * inv);
    }
  }
}

extern "C" void kernel_launch(void* const* d_in, const int* in_sizes, int n_in,
                              void* d_out, int out_size, void* d_ws,
                              size_t ws_size, hipStream_t stream) {
  const float* feat = (const float*)d_in[0];
  const float* W1   = (const float*)d_in[1];
  const float* b1   = (const float*)d_in[2];
  const float* W2   = (const float*)d_in[3];
  const float* b2   = (const float*)d_in[4];
  const float* pi   = (const float*)d_in[5];
  float* out = (float*)d_out;

  char* ws = (char*)d_ws;
  ushort* W1T_buf  = (ushort*)(ws);                                // 2 MB
  ushort* W2T_buf  = (ushort*)(ws + ((size_t)2 << 20));            // 2 MB
  ushort* lpT_buf  = (ushort*)(ws + ((size_t)4 << 20));            // 1.75 MB
  float*  part_buf = (float*)(ws + ((size_t)6 << 20));             // 6.25 MB
  unsigned int* cnt_buf =
      (unsigned int*)(ws + ((size_t)13 << 20));                    // 128 B

  hipMemsetAsync(cnt_buf, 0, 128, stream);   // zero arrival counters

  k_prep<<<768, 256, 0, stream>>>(W1, W2, pi, W1T_buf, W2T_buf, lpT_buf);
  k12_mfma<<<512, 512, 0, stream>>>(feat, W1T_buf, b1, W2T_buf, b2,
                                    lpT_buf, part_buf, cnt_buf, out);
}

// Round 14
// 108.207 us; speedup vs baseline: 1.2812x; 1.2812x over previous
//
#include <hip/hip_runtime.h>
#include <hip/hip_bf16.h>
#include <math.h>

#define T_ 16
#define B_ 1024
#define F_ 512
#define H_ 128
#define D_ 8
#define C_ 100
#define L_ 512
#define CP_ 112   // C padded to multiple of 16 for MFMA N

typedef __attribute__((ext_vector_type(8))) short bf16x8_t;
typedef __attribute__((ext_vector_type(4))) float f32x4_t;

__device__ inline ushort f2bf(float x) {
  __hip_bfloat16 b = __float2bfloat16(x);
  return *(ushort*)&b;
}
__device__ inline float bf2f(ushort u) {
  union { unsigned int i; float f; } v;
  v.i = ((unsigned int)u) << 16;
  return v.f;
}

// Raw barrier helpers: NO vmcnt drain (prefetch loads stay in flight).
__device__ inline void bar_raw() {
  asm volatile("" ::: "memory");
  __builtin_amdgcn_s_barrier();
  asm volatile("" ::: "memory");
}
__device__ inline void bar_publish_lds() {
  asm volatile("s_waitcnt lgkmcnt(0)" ::: "memory");
  __builtin_amdgcn_s_barrier();
  asm volatile("" ::: "memory");
}

// ---------------------------------------------------------------------------
// k_prep (r13 vectorized version, measured-good): 64x64 f32 transpose tiles,
// float4 loads (16B/lane), bf16x8 stores.  Grid 768.
//   [0,256)    : W1 [t][F][H] -> W1T [t][H][F] bf16
//   [256,512)  : W2 [t][H][L] -> W2T [t][L][H] bf16
//   [512,768)  : softmax(pi) -> lpT[t][c][l], coalesced 16B stores.
// ---------------------------------------------------------------------------
__global__ __launch_bounds__(256) void k_prep(
    const float* __restrict__ W1, const float* __restrict__ W2,
    const float* __restrict__ pi, ushort* __restrict__ W1T,
    ushort* __restrict__ W2T, ushort* __restrict__ lpT) {
  __shared__ float tile[64][68];                     // 17408 B
  ushort (*tileT)[48] = (ushort(*)[48])tile;         // softmax path alias
  const int bid = blockIdx.x, tid = threadIdx.x;

  if (bid < 512) {  // ---- transposes, 64x64 tiles
    const float* X; ushort* XT; int K, N, kb, nb, s;
    if (bid < 256) {
      int u = bid & 15;  kb = u & 7;  nb = (u >> 3) & 1;  s = bid >> 4;
      X = W1; XT = W1T; K = F_; N = H_;
    } else {
      int r = bid - 256; int u = r & 15; kb = u & 1; nb = (u >> 1) & 7; s = r >> 4;
      X = W2; XT = W2T; K = H_; N = L_;
    }
    const int k0 = kb * 64, n0 = nb * 64;
    const float* Xs = X + (size_t)s * K * N;
    ushort* XTs = XT + (size_t)s * N * K;
    {
      const int rrow = tid >> 4, c4 = (tid & 15) * 4;
#pragma unroll
      for (int j = 0; j < 4; ++j) {
        float4 v = *(const float4*)(Xs + (size_t)(k0 + j * 16 + rrow) * N + n0 + c4);
        *(float4*)&tile[j * 16 + rrow][c4] = v;
      }
    }
    __syncthreads();
    {
      const int k8 = (tid & 7) * 8;
#pragma unroll
      for (int pass = 0; pass < 2; ++pass) {
        int rr = pass * 32 + (tid >> 3);
        bf16x8_t o;
#pragma unroll
        for (int i = 0; i < 8; ++i) o[i] = (short)f2bf(tile[k8 + i][rr]);
        *(bf16x8_t*)(XTs + (size_t)(n0 + rr) * K + k0 + k8) = o;
      }
    }
    return;
  }
  {  // ---- softmax of 32 rows -> LDS transpose -> coalesced lpT[t][c][l]
    int bid2 = bid - 512;                  // [0,256)
    int t = bid2 >> 4, l0 = (bid2 & 15) << 5;
    int lane = tid & 63;
#pragma unroll
    for (int p = 0; p < 8; ++p) {
      int rl = p * 4 + (tid >> 6);
      const float* x = pi + (size_t)(t * L_ + l0 + rl) * C_;
      float v0 = (lane < C_) ? x[lane] : -1e30f;
      float v1 = (lane + 64 < C_) ? x[lane + 64] : -1e30f;
      float m = fmaxf(v0, v1);
#pragma unroll
      for (int off = 32; off; off >>= 1) m = fmaxf(m, __shfl_xor(m, off, 64));
      float e0 = __expf(v0 - m);
      float e1 = (lane + 64 < C_) ? __expf(v1 - m) : 0.0f;
      float sm = e0 + e1;
#pragma unroll
      for (int off = 32; off; off >>= 1) sm += __shfl_xor(sm, off, 64);
      float inv = 1.0f / sm;
      if (lane < C_) tileT[lane][rl] = f2bf(e0 * inv);
      int c2 = lane + 64;
      if (c2 < CP_) tileT[c2][rl] = f2bf(c2 < C_ ? e1 * inv : 0.0f);
    }
    __syncthreads();
    ushort* dst = lpT + (size_t)t * CP_ * L_ + l0;
    for (int idx = tid; idx < 448; idx += 256) {       // 112 c x 4 chunks
      int c = idx >> 2, ch = (idx & 3) * 8;
      *(bf16x8_t*)(dst + (size_t)c * L_ + ch) = *(const bf16x8_t*)&tileT[c][ch];
    }
  }
}

// ---------------------------------------------------------------------------
// k12 (r11 verbatim — plateau-best): dbuf LDS staging, counted-vmcnt raw
// barriers, 2-ahead prefetch, fused feat fp32->bf16 cvt, plain part stores.
// Both k6 fusions (atomic r12, last-block r13) regressed via cross-XCD
// coherence traffic -- 3-kernel split is structurally right.
// ---------------------------------------------------------------------------
__global__ __launch_bounds__(512, 4) void k12_mfma(
    const float* __restrict__ feat, const ushort* __restrict__ W1T,
    const float* __restrict__ b1, const ushort* __restrict__ W2T,
    const float* __restrict__ b2, const ushort* __restrict__ lpT,
    float* __restrict__ part) {
  __shared__ ushort smem[38400];                        // 76800 B
  ushort (*h_s)[136] = (ushort(*)[136])smem;
  ushort (*a_s0)[72] = (ushort(*)[72])(smem + 4352);
  ushort (*a_s1)[72] = (ushort(*)[72])(smem + 4352 + 2304);
  ushort (*b_s0)[72] = (ushort(*)[72])(smem + 8960);
  ushort (*b_s1)[72] = (ushort(*)[72])(smem + 8960 + 9216);
  ushort (*w_s0)[136] = (ushort(*)[136])(smem + 4352);
  ushort (*w_s1)[136] = (ushort(*)[136])(smem + 4352 + 8704);
  ushort (*p_s)[520] = (ushort(*)[520])(smem + 21760);

  const int bid = blockIdx.x;
  const int t = bid & 15, b0 = (bid >> 4) * 32;
  const int tid = threadIdx.x;                          // [0,512)
  const int w = tid >> 6, lane = tid & 63, quad = lane >> 4, n = lane & 15;

  // ---------------- phase 1: h tile (M=32, N=128, K=512) ----------------
  {
    const bool doA = tid < 256;
    const int srow = tid >> 3, scol = (tid & 7) * 8;    // srow: A [0,32), B [0,64)
    const float*  fp32p = feat + (size_t)(b0 + srow) * F_ + scol;   // tid<256
    const ushort* w1p   = W1T + ((size_t)t * H_ + srow) * F_ + scol;

    float4 ra[2][2];           // fp32 A prefetch (2 sets x 8 floats)
    bf16x8_t rb[2][2];         // B prefetch (2 sets x 2 rows)

    // chunk 0 -> set 0, stage immediately (exposed once)
    if (doA) { ra[0][0] = *(const float4*)(fp32p);
               ra[0][1] = *(const float4*)(fp32p + 4); }
#pragma unroll
    for (int i = 0; i < 2; ++i)
      rb[0][i] = *(const bf16x8_t*)(w1p + (size_t)i * 64 * F_);
    if (doA) {
      bf16x8_t o;
      o[0] = (short)f2bf(ra[0][0].x); o[1] = (short)f2bf(ra[0][0].y);
      o[2] = (short)f2bf(ra[0][0].z); o[3] = (short)f2bf(ra[0][0].w);
      o[4] = (short)f2bf(ra[0][1].x); o[5] = (short)f2bf(ra[0][1].y);
      o[6] = (short)f2bf(ra[0][1].z); o[7] = (short)f2bf(ra[0][1].w);
      *(bf16x8_t*)&a_s0[srow][scol] = o;
    }
#pragma unroll
    for (int i = 0; i < 2; ++i)
      *(bf16x8_t*)&b_s0[i * 64 + srow][scol] = rb[0][i];
    bar_publish_lds();                         // B1: chunk 0 visible
    // prefetch chunk 1 -> set 1, chunk 2 -> set 0
    if (doA) { ra[1][0] = *(const float4*)(fp32p + 64);
               ra[1][1] = *(const float4*)(fp32p + 68); }
#pragma unroll
    for (int i = 0; i < 2; ++i)
      rb[1][i] = *(const bf16x8_t*)(w1p + (size_t)i * 64 * F_ + 64);
    if (doA) { ra[0][0] = *(const float4*)(fp32p + 128);
               ra[0][1] = *(const float4*)(fp32p + 132); }
#pragma unroll
    for (int i = 0; i < 2; ++i)
      rb[0][i] = *(const bf16x8_t*)(w1p + (size_t)i * 64 * F_ + 128);

    f32x4_t acc[2];
    acc[0] = (f32x4_t){0.f, 0.f, 0.f, 0.f};
    acc[1] = (f32x4_t){0.f, 0.f, 0.f, 0.f};
#pragma unroll
    for (int kc = 0; kc < 8; ++kc) {
      ushort (*ar)[72] = (kc & 1) ? a_s1 : a_s0;
      ushort (*br)[72] = (kc & 1) ? b_s1 : b_s0;
#pragma unroll
      for (int ks2 = 0; ks2 < 2; ++ks2) {
        const int ko = ks2 * 32 + quad * 8;
        bf16x8_t af0 = *(const bf16x8_t*)&ar[n][ko];
        bf16x8_t af1 = *(const bf16x8_t*)&ar[16 + n][ko];
        bf16x8_t bfr = *(const bf16x8_t*)&br[w * 16 + n][ko];
        acc[0] = __builtin_amdgcn_mfma_f32_16x16x32_bf16(af0, bfr, acc[0],
                                                         0, 0, 0);
        acc[1] = __builtin_amdgcn_mfma_f32_16x16x32_bf16(af1, bfr, acc[1],
                                                         0, 0, 0);
      }
      if (kc < 7) {                            // stage chunk kc+1 -> other buf
        const int p = (kc + 1) & 1;
        ushort (*aw)[72] = p ? a_s1 : a_s0;
        ushort (*bw)[72] = p ? b_s1 : b_s0;
        if (doA) {
          bf16x8_t o;
          o[0] = (short)f2bf(ra[p][0].x); o[1] = (short)f2bf(ra[p][0].y);
          o[2] = (short)f2bf(ra[p][0].z); o[3] = (short)f2bf(ra[p][0].w);
          o[4] = (short)f2bf(ra[p][1].x); o[5] = (short)f2bf(ra[p][1].y);
          o[6] = (short)f2bf(ra[p][1].z); o[7] = (short)f2bf(ra[p][1].w);
          *(bf16x8_t*)&aw[srow][scol] = o;     // counted vmcnt via reg dep
        }
#pragma unroll
        for (int i = 0; i < 2; ++i)
          *(bf16x8_t*)&bw[i * 64 + srow][scol] = rb[p][i];
        bar_publish_lds();                     // ONE barrier per phase
        if (kc < 6) {                          // refill set p with chunk kc+3
          if (doA) { ra[p][0] = *(const float4*)(fp32p + (kc + 3) * 64);
                     ra[p][1] = *(const float4*)(fp32p + (kc + 3) * 64 + 4); }
#pragma unroll
          for (int i = 0; i < 2; ++i)
            rb[p][i] = *(const bf16x8_t*)(w1p + (size_t)i * 64 * F_ + (kc + 3) * 64);
        }
      }
    }
    float bias = b1[t * H_ + w * 16 + n];
#pragma unroll
    for (int mt = 0; mt < 2; ++mt)
#pragma unroll
      for (int r = 0; r < 4; ++r) {
        float v = acc[mt][r] + bias;
        h_s[mt * 16 + quad * 4 + r][w * 16 + n] = f2bf(v > 0.f ? v : 0.f);
      }
  }

  // ---------------- phase 2: GEMM2 + sigmoid -> p_s (dbuf w_s) ----------
  {
    const int wrow = tid >> 4, wcol = (tid & 15) * 8;  // wrow in [0,32)
    const ushort* w2p = W2T + ((size_t)t * L_ + wrow) * H_ + wcol;
    bf16x8_t rw[2][2];
    // issue nc=0,1 loads NOW: fly under the h_s epilogue + barrier
#pragma unroll
    for (int i = 0; i < 2; ++i)
      rw[0][i] = *(const bf16x8_t*)(w2p + (size_t)(i * 32) * H_);
#pragma unroll
    for (int i = 0; i < 2; ++i)
      rw[1][i] = *(const bf16x8_t*)(w2p + (size_t)(64 + i * 32) * H_);
    bar_publish_lds();                         // B2: h_s visible, ph1 dead

    const int mhalf = w >> 2, lhalf = w & 3;   // 2 m-halves x 4 l-tiles
    bf16x8_t af2[4];                           // A frags hoisted
#pragma unroll
    for (int ks = 0; ks < 4; ++ks)
      af2[ks] = *(const bf16x8_t*)&h_s[mhalf * 16 + n][ks * 32 + quad * 8];
#pragma unroll
    for (int i = 0; i < 2; ++i)
      *(bf16x8_t*)&w_s0[i * 32 + wrow][wcol] = rw[0][i];
    bar_publish_lds();                         // w_s(0) visible
#pragma unroll
    for (int i = 0; i < 2; ++i)                // refill set 0 with nc=2
      rw[0][i] = *(const bf16x8_t*)(w2p + (size_t)(128 + i * 32) * H_);

#pragma unroll
    for (int nc = 0; nc < 8; ++nc) {
      ushort (*wr)[136] = (nc & 1) ? w_s1 : w_s0;
      f32x4_t acc = (f32x4_t){0.f, 0.f, 0.f, 0.f};
#pragma unroll
      for (int ks = 0; ks < 4; ++ks) {
        bf16x8_t bfrag = *(const bf16x8_t*)&wr[lhalf * 16 + n][ks * 32 + quad * 8];
        acc = __builtin_amdgcn_mfma_f32_16x16x32_bf16(af2[ks], bfrag, acc,
                                                      0, 0, 0);
      }
      int l = nc * 64 + lhalf * 16 + n;
      float bias = b2[t * L_ + l];
#pragma unroll
      for (int r = 0; r < 4; ++r) {
        float x = acc[r] + bias;
        p_s[mhalf * 16 + quad * 4 + r][l] = f2bf(1.0f / (1.0f + __expf(-x)));
      }
      if (nc < 7) {                            // stage nc+1 -> other buf
        const int p = (nc + 1) & 1;
        ushort (*ww)[136] = p ? w_s1 : w_s0;
#pragma unroll
        for (int i = 0; i < 2; ++i)
          *(bf16x8_t*)&ww[i * 32 + wrow][wcol] = rw[p][i];
        bar_publish_lds();                     // ONE barrier per phase
        if (nc < 6) {
#pragma unroll
          for (int i = 0; i < 2; ++i)
            rw[p][i] = *(const bf16x8_t*)(w2p + (size_t)((nc + 3) * 64 + i * 32) * H_);
        }
      }
    }
  }
  bar_publish_lds();                           // B3: p_s complete

  // ---------------- routing: 1024 units (b,s) over 512 threads, 2 passes --
  bf16x8_t mo[2][2];
#pragma unroll
  for (int pass = 0; pass < 2; ++pass) {
    int unit = pass * 512 + tid;
    int b = unit >> 5;
    int s = unit & 31;
    float P = 1.f;
#pragma unroll
    for (int d = 0; d < 5; ++d) {
      int nd = (1 << d) - 1 + (s >> (5 - d));
      int sd = (s >> (4 - d)) & 1;
      float pv = bf2f(p_s[b][nd]);
      P *= sd ? (1.f - pv) : pv;
    }
    float p5 = bf2f(p_s[b][31 + s]);
    float q5[2] = {P * p5, P * (1.f - p5)};
    float q6[4], q7[8];
#pragma unroll
    for (int j = 0; j < 2; ++j) {
      float pv = bf2f(p_s[b][63 + 2 * s + j]);
      q6[2 * j] = q5[j] * pv;
      q6[2 * j + 1] = q5[j] * (1.f - pv);
    }
#pragma unroll
    for (int u = 0; u < 4; ++u) {
      float pv = bf2f(p_s[b][127 + 4 * s + u]);
      q7[2 * u] = q6[u] * pv;
      q7[2 * u + 1] = q6[u] * (1.f - pv);
    }
    bf16x8_t o0, o1;
#pragma unroll
    for (int v = 0; v < 8; ++v) {
      float pv = bf2f(p_s[b][255 + 8 * s + v]);
      ushort e0 = f2bf(q7[v] * pv);
      ushort e1 = f2bf(q7[v] * (1.f - pv));
      if (v < 4) { o0[2 * v] = (short)e0; o0[2 * v + 1] = (short)e1; }
      else       { o1[2 * (v - 4)] = (short)e0; o1[2 * (v - 4) + 1] = (short)e1; }
    }
    mo[pass][0] = o0;
    mo[pass][1] = o1;
  }
  bar_raw();         // B4: routing reads done -> safe to overwrite p_s
#pragma unroll
  for (int pass = 0; pass < 2; ++pass) {
    int unit = pass * 512 + tid;
    int b = unit >> 5;
    int s = unit & 31;
    *(bf16x8_t*)&p_s[b][s * 16]     = mo[pass][0];   // p_s now holds mu
    *(bf16x8_t*)&p_s[b][s * 16 + 8] = mo[pass][1];
  }
  bar_publish_lds();                           // B5: mu visible

  // ---------------- GEMM3: part = mu @ leaf_p (M=32,N=112,K=512) ----------
  // 14 (mt,nt) units over 8 waves: wave w does unit w, and unit w+8 if w<6.
  {
#pragma unroll
    for (int uu = 0; uu < 2; ++uu) {
      int u = w + uu * 8;
      if (u < 14) {
        const int mt = u & 1, nt = u >> 1;
        const ushort* arow = &p_s[mt * 16 + n][0];
        const ushort* brow = lpT + (size_t)t * CP_ * L_ +
                             ((size_t)(nt * 16 + n)) * L_ + quad * 8;
        f32x4_t acc = (f32x4_t){0.f, 0.f, 0.f, 0.f};
#pragma unroll 4
        for (int k = 0; k < L_; k += 32) {
          bf16x8_t af = *(const bf16x8_t*)(arow + k + quad * 8);
          bf16x8_t bfr = *(const bf16x8_t*)(brow + k);
          acc = __builtin_amdgcn_mfma_f32_16x16x32_bf16(af, bfr, acc, 0, 0, 0);
        }
        const int m0 = b0 + mt * 16 + quad * 4;
        const int c = nt * 16 + n;
        if (c < C_) {
#pragma unroll
          for (int r = 0; r < 4; ++r)
            part[((size_t)t * B_ + m0 + r) * C_ + c] = acc[r];
        }
      }
    }
  }
}

// ---------------------------------------------------------------------------
// k6: out[b][c] = log( (sum_t part[t][b][c]) / (L*T) ), float4-vectorized
// (per-element sum order unchanged -> bit-identical).
// ---------------------------------------------------------------------------
__global__ __launch_bounds__(256) void k6_log(
    const float* __restrict__ part, float* __restrict__ out) {
  int i = (blockIdx.x * 256 + threadIdx.x) * 4;
  if (i < B_ * C_) {
    float4 s = {0.f, 0.f, 0.f, 0.f};
#pragma unroll
    for (int t = 0; t < T_; ++t) {
      float4 v = *(const float4*)(part + (size_t)t * B_ * C_ + i);
      s.x += v.x; s.y += v.y; s.z += v.z; s.w += v.w;
    }
    const float inv = 1.0f / (L_ * T_);
    float4 o;
    o.x = logf(s.x * inv); o.y = logf(s.y * inv);
    o.z = logf(s.z * inv); o.w = logf(s.w * inv);
    *(float4*)(out + i) = o;
  }
}

extern "C" void kernel_launch(void* const* d_in, const int* in_sizes, int n_in,
                              void* d_out, int out_size, void* d_ws,
                              size_t ws_size, hipStream_t stream) {
  const float* feat = (const float*)d_in[0];
  const float* W1   = (const float*)d_in[1];
  const float* b1   = (const float*)d_in[2];
  const float* W2   = (const float*)d_in[3];
  const float* b2   = (const float*)d_in[4];
  const float* pi   = (const float*)d_in[5];
  float* out = (float*)d_out;

  char* ws = (char*)d_ws;
  ushort* W1T_buf  = (ushort*)(ws);                                // 2 MB
  ushort* W2T_buf  = (ushort*)(ws + ((size_t)2 << 20));            // 2 MB
  ushort* lpT_buf  = (ushort*)(ws + ((size_t)4 << 20));            // 1.75 MB
  float*  part_buf = (float*)(ws + ((size_t)6 << 20));             // 6.25 MB

  k_prep<<<768, 256, 0, stream>>>(W1, W2, pi, W1T_buf, W2T_buf, lpT_buf);
  k12_mfma<<<512, 512, 0, stream>>>(feat, W1T_buf, b1, W2T_buf, b2,
                                    lpT_buf, part_buf);
  k6_log<<<(B_ * C_ / 4 + 255) / 256, 256, 0, stream>>>(part_buf, out);
}